// Round 5
// baseline (367.821 us; speedup 1.0000x reference)
//
#include <hip/hip_runtime.h>
#include <hip/hip_bf16.h>

typedef __attribute__((ext_vector_type(8))) short short8;
typedef __attribute__((ext_vector_type(4))) float f32x4;
typedef __attribute__((ext_vector_type(16))) float f32x16;
typedef __attribute__((ext_vector_type(4))) unsigned int u32x4;

#define NB 8
#define NC 256
#define NNN 4096
#define L2E 1.44269504088896f

__device__ __forceinline__ ushort f2bf(float f) {
  __hip_bfloat16 h = __float2bfloat16(f);
  return *reinterpret_cast<ushort*>(&h);
}
__device__ __forceinline__ unsigned pack2(float a, float b) {
  return (unsigned)f2bf(a) | ((unsigned)f2bf(b) << 16);
}
__device__ __forceinline__ void gload16(const void* g, void* l) {
  __builtin_amdgcn_global_load_lds(
      (const __attribute__((address_space(1))) void*)g,
      (__attribute__((address_space(3))) void*)l, 16, 0, 0);
}

// fTs[b][n][c ^ ((n&7)<<3)] = bf16(x[b][c][n])   (chunk-swizzled rows, 512B)
__global__ __launch_bounds__(256) void prep_T(const float* __restrict__ x,
                                              ushort* __restrict__ fTs) {
  __shared__ float tile[32][33];
  const int tx = threadIdx.x, ty = threadIdx.y;
  const int n0 = blockIdx.x * 32, c0 = blockIdx.y * 32, b = blockIdx.z;
#pragma unroll
  for (int k = 0; k < 4; ++k) {
    tile[ty + 8 * k][tx] =
        x[((size_t)(b * NC + c0 + ty + 8 * k)) * NNN + n0 + tx];
  }
  __syncthreads();
#pragma unroll
  for (int k = 0; k < 4; ++k) {
    const int n = n0 + ty + 8 * k;
    const int c = c0 + tx;
    fTs[(size_t)(b * NNN + n) * NC + (c ^ ((n & 7) << 3))] =
        f2bf(tile[tx][ty + 8 * k]);
  }
}

// fVs[b][c][64t + (mm ^ ((c&7)<<3))] = bf16(x[b][c][64t+mm])
__global__ __launch_bounds__(256) void prep_V(const float* __restrict__ x,
                                              ushort* __restrict__ fVs) {
  const size_t ci = (size_t)blockIdx.x * 256 + threadIdx.x;  // 1M chunks
  const int p = (int)(ci & 511);
  const int c = (int)((ci >> 9) & 255);
  const int b = (int)(ci >> 17);
  const int lp = (p & ~7) | ((p & 7) ^ (c & 7));  // logical chunk
  const float* src = x + ((size_t)(b * NC + c)) * NNN + lp * 8;
  f32x4 a0 = *(const f32x4*)src;
  f32x4 a1 = *(const f32x4*)(src + 4);
  short8 w;
  w[0] = (short)f2bf(a0[0]); w[1] = (short)f2bf(a0[1]);
  w[2] = (short)f2bf(a0[2]); w[3] = (short)f2bf(a0[3]);
  w[4] = (short)f2bf(a1[0]); w[5] = (short)f2bf(a1[1]);
  w[6] = (short)f2bf(a1[2]); w[7] = (short)f2bf(a1[3]);
  *(short8*)(fVs + ((size_t)(b * NC + c)) * NNN + p * 8) = w;
}

// Flash attention, 32x32x16 MFMA, swapped QK^T, O^T accumulation.
// 512 threads = 8 waves = 4 n-groups x 2 m-halves. Grid 256 (1 block/CU,
// 2 waves/SIMD). LDS: dbuf 2x{K 32KB + V 32KB} = 128KB + 1KB stats.
__global__ __launch_bounds__(512, 2) void attn_kernel(
    const float* __restrict__ x, const ushort* __restrict__ fTs,
    const ushort* __restrict__ fVs, const float* __restrict__ gamma,
    float* __restrict__ out) {
  __shared__ __align__(16) char smem[132096];
  float* stats = (float*)(smem + 131072);

  const int tid = threadIdx.x;
  const int w8 = tid >> 6;   // wave 0..7
  const int g = w8 >> 1;     // n-group 0..3
  const int mh = w8 & 1;     // m-half 0..1
  const int l = tid & 63;
  const int l31 = l & 31;
  const int h = l >> 5;
  const int b = blockIdx.x & 7;             // batch -> XCD
  const int gn0 = (blockIdx.x >> 3) * 128;  // query-row base of block
  const int n0w = gn0 + g * 32;             // this wave's 32 query rows

  const char* fTb = (const char*)(fTs + (size_t)b * NNN * NC);
  const char* fVb = (const char*)(fVs + (size_t)b * NNN * NC);

  // Q fragments (B operand): col n = l31 -> row n0w+l31; k = kc*16+8h+j
  short8 q[16];
  {
    const int n = n0w + l31;
    const char* qrow = fTb + (size_t)n * 512;
    const int sw = (l31 & 7) << 4;
#pragma unroll
    for (int kc = 0; kc < 16; ++kc)
      q[kc] = *(const short8*)(qrow + ((kc * 32 + 16 * h) ^ sw));
  }

  // O^T accumulator: rows c = cf*32 + (r&3)+8*(r>>2)+4h, cols n = l31
  f32x16 o[8];
#pragma unroll
  for (int cf = 0; cf < 8; ++cf)
#pragma unroll
    for (int r = 0; r < 16; ++r) o[cf][r] = 0.f;
  float m_run = -3.0e38f, l_half = 0.f;

  // DMA staging: linear 64KB tile image {K 32KB}{V 32KB}
  const char* kSrc = fTb + tid * 16;
  const char* vSrc = fVb + (size_t)(l >> 3) * 8192 + (l & 7) * 16;
  const int dstW = w8 << 10;  // per-wave 1KB slot within each 8KB stripe

  // prologue: tile 0 -> buffer 0
#pragma unroll
  for (int i = 0; i < 4; ++i)
    gload16(kSrc + i * 8192, smem + dstW + i * 8192);
#pragma unroll
  for (int i = 0; i < 4; ++i)
    gload16(vSrc + (size_t)(i * 8 + w8) * 65536, smem + 32768 + dstW + i * 8192);
  __syncthreads();

  const int krow = mh * 32 + l31;
  const int ksw = (l31 & 7) << 4;

  for (int t = 0; t < 64; ++t) {
    char* bufC = smem + (t & 1) * 65536;
    // issue next tile's DMA; stays in flight across the mid-tile s_barrier
    if (t < 63) {
      char* bufN = smem + ((t + 1) & 1) * 65536;
      const size_t kOff = (size_t)(t + 1) * 32768;
      const size_t vOff = (size_t)(t + 1) * 128;
#pragma unroll
      for (int i = 0; i < 4; ++i)
        gload16(kSrc + kOff + i * 8192, bufN + dstW + i * 8192);
#pragma unroll
      for (int i = 0; i < 4; ++i)
        gload16(vSrc + (size_t)(i * 8 + w8) * 65536 + vOff,
                bufN + 32768 + dstW + i * 8192);
    }

    // ---- S^T = K(m-half) * Q^T : 16 MFMAs ----
    f32x16 s;
#pragma unroll
    for (int r = 0; r < 16; ++r) s[r] = 0.f;
#pragma unroll
    for (int kc = 0; kc < 16; ++kc) {
      short8 ka =
          *(const short8*)(bufC + krow * 512 + ((kc * 32 + 16 * h) ^ ksw));
      s = __builtin_amdgcn_mfma_f32_32x32x16_bf16(ka, q[kc], s, 0, 0, 0);
    }

    // ---- pair-shared online softmax (per-lane n stats) ----
    float tm = s[0];
#pragma unroll
    for (int r = 1; r < 16; ++r) tm = fmaxf(tm, s[r]);
    tm = fmaxf(tm, __shfl_xor(tm, 32));
    stats[w8 * 32 + l31] = tm;
    __builtin_amdgcn_sched_barrier(0);
    asm volatile("s_waitcnt lgkmcnt(0)" ::: "memory");
    __builtin_amdgcn_s_barrier();  // no vmcnt drain: DMA stays in flight
    __builtin_amdgcn_sched_barrier(0);
    const float pm = stats[(w8 * 32 + l31) ^ 32];
    const float mc = fmaxf(tm, pm);

    if (__any(mc > m_run + 8.f)) {  // T13 defer-max
      const float mnew = fmaxf(m_run, mc);
      const float alpha = exp2f((m_run - mnew) * L2E);
      m_run = mnew;
      l_half *= alpha;
#pragma unroll
      for (int cf = 0; cf < 8; ++cf)
#pragma unroll
        for (int r = 0; r < 16; ++r) o[cf][r] *= alpha;  // lane-local!
    }

    float rsum = 0.f;
#pragma unroll
    for (int r = 0; r < 16; ++r) {
      const float pv = exp2f((s[r] - m_run) * L2E);
      s[r] = pv;
      rsum += pv;
    }
    rsum += __shfl_xor(rsum, 32);
    l_half += rsum;

    // ---- pack P, exchange m-quads with lane^32, PV: O^T += V^T * P ----
    const char* Vp = bufC + 32768;
#pragma unroll
    for (int ks = 0; ks < 2; ++ks) {
      const int ok = 8 * ks + 4 * h;        // regs kept in-frag
      const int os = 8 * ks + 4 * (1 - h);  // regs sent to partner
      const unsigned uA = pack2(s[ok], s[ok + 1]);
      const unsigned uB = pack2(s[ok + 2], s[ok + 3]);
      const unsigned vA = pack2(s[os], s[os + 1]);
      const unsigned vB = pack2(s[os + 2], s[os + 3]);
      const unsigned xA = (unsigned)__shfl_xor((int)vA, 32);
      const unsigned xB = (unsigned)__shfl_xor((int)vB, 32);
      u32x4 fu;
      if (h == 0) { fu[0] = uA; fu[1] = uB; fu[2] = xA; fu[3] = xB; }
      else        { fu[0] = xA; fu[1] = xB; fu[2] = uA; fu[3] = uB; }
      const short8 pb = __builtin_bit_cast(short8, fu);
      const int mb = mh * 64 + ks * 32 + 16 * h;
#pragma unroll
      for (int cf = 0; cf < 8; ++cf) {
        const int c = cf * 32 + l31;
        const short8 va =
            *(const short8*)(Vp + c * 128 + (mb ^ ((c & 7) << 4)));
        o[cf] = __builtin_amdgcn_mfma_f32_32x32x16_bf16(va, pb, o[cf], 0, 0, 0);
      }
    }
    __syncthreads();  // drains this tile's DMA (full-tile window)
  }

  // ---- epilogue: merge m-halves via LDS, normalize, store coalesced ----
  stats[w8 * 32 + l31] = l_half;
  if (mh == 1) {
    float* Og = (float*)(smem + g * 32768);
#pragma unroll
    for (int cf = 0; cf < 8; ++cf)
#pragma unroll
      for (int r = 0; r < 16; ++r) {
        const int c = cf * 32 + (r & 3) + 8 * (r >> 2) + 4 * h;
        Og[c * 32 + l31] = o[cf][r];
      }
  }
  __syncthreads();
  if (mh == 0) {
    const float l_tot = stats[g * 64 + l31] + stats[g * 64 + 32 + l31];
    const float sc = gamma[0] / l_tot;
    const float* Og = (const float*)(smem + g * 32768);
#pragma unroll
    for (int cf = 0; cf < 8; ++cf)
#pragma unroll
      for (int r = 0; r < 16; ++r) {
        const int c = cf * 32 + (r & 3) + 8 * (r >> 2) + 4 * h;
        const float val = (o[cf][r] + Og[c * 32 + l31]) * sc;
        const size_t gi = ((size_t)(b * NC + c)) * NNN + n0w + l31;
        out[gi] = val + x[gi];
      }
  }
}

extern "C" void kernel_launch(void* const* d_in, const int* in_sizes, int n_in,
                              void* d_out, int out_size, void* d_ws,
                              size_t ws_size, hipStream_t stream) {
  const float* x = (const float*)d_in[0];
  const float* gamma = (const float*)d_in[1];
  float* out = (float*)d_out;
  ushort* fTs = (ushort*)d_ws;                          // 16.78 MB
  ushort* fVs = (ushort*)d_ws + (size_t)NB * NNN * NC;  // + 16.78 MB

  dim3 pg(NNN / 32, NC / 32, NB);
  dim3 pb(32, 8, 1);
  prep_T<<<pg, pb, 0, stream>>>(x, fTs);
  prep_V<<<dim3(4096), dim3(256), 0, stream>>>(x, fVs);

  attn_kernel<<<dim3(256), dim3(512), 0, stream>>>(x, fTs, fVs, gamma, out);
}